// Round 3
// baseline (81.556 us; speedup 1.0000x reference)
//
#include <hip/hip_runtime.h>
#include <math.h>

#define N 1024
#define B 32
#define JC 8            // k1 j-chunks per row
#define K1CHUNK 128     // N / JC
#define NSL 16          // j-slices per i (tid & 15)
#define SIGMA 1.0f
#define FEPS 1.1920928955078125e-07f   // np.finfo(float32).eps
#define LOG2E 1.4426950408889634f

#if defined(__has_builtin) && __has_builtin(__builtin_amdgcn_exp2f)
#define EXP2F(x) __builtin_amdgcn_exp2f(x)
#else
#define EXP2F(x) exp2f(x)
#endif

// Monotone-increasing uint mapping of float (no NaNs in input).
__device__ __forceinline__ unsigned fkey(float f) {
    unsigned u = __float_as_uint(f);
    return (u & 0x80000000u) ? ~u : (u | 0x80000000u);
}

// K1: partial stable-descending-rank counts over j-chunks; per-row sum(a).
// Rank condition (a_j > a_i) || (a_j == a_i && j < i) folded into ONE u64
// compare: K = (fkey(a) << 32) | (N-1-idx);  K_j > K_i  <=>  rank condition.
__global__ __launch_bounds__(256) void k1_rank(const float* __restrict__ a,
                                               int* __restrict__ rank_part,
                                               float* __restrict__ row_sum) {
    const int bx = blockIdx.x;
    const int r = bx >> 3, jc = bx & 7;
    const int tid = threadIdx.x;
    const float* __restrict__ arow = a + r * N;

    __shared__ unsigned long long sK[K1CHUNK];
    if (tid < K1CHUNK) {
        const int jg = jc * K1CHUNK + tid;
        sK[tid] = ((unsigned long long)fkey(arow[jg]) << 32) |
                  (unsigned)(N - 1 - jg);
    }

    float ai[4];
    unsigned long long Ki[4];
    int ig[4];
#pragma unroll
    for (int k = 0; k < 4; k++) {
        ig[k] = tid + k * 256;
        ai[k] = arow[ig[k]];
        Ki[k] = ((unsigned long long)fkey(ai[k]) << 32) |
                (unsigned)(N - 1 - ig[k]);
    }
    __syncthreads();

    int cnt[4] = {0, 0, 0, 0};
#pragma unroll 4
    for (int j = 0; j < K1CHUNK; j++) {
        const unsigned long long Kj = sK[j];
#pragma unroll
        for (int k = 0; k < 4; k++) cnt[k] += (Kj > Ki[k]) ? 1 : 0;
    }
#pragma unroll
    for (int k = 0; k < 4; k++)
        rank_part[(jc * B + r) * N + ig[k]] = cnt[k];

    if (jc == 0) {
        float s = ai[0] + ai[1] + ai[2] + ai[3];
#pragma unroll
        for (int off = 32; off >= 1; off >>= 1) s += __shfl_down(s, off, 64);
        __shared__ float wsum[4];
        if ((tid & 63) == 0) wsum[tid >> 6] = s;
        __syncthreads();
        if (tid == 0) row_sum[r] = wsum[0] + wsum[1] + wsum[2] + wsum[3];
    }
}

// K2: fused prep + pairwise gradient, y-sorted slot order (round-1 structure)
// + REGISTER BLOCKING: each lane owns TWO adjacent slots (i0, i1), so one
// ds_read_b128 of sdat[j] feeds 2 pairs -> phase-B LDS issue (the measured
// bottleneck, ~12cyc/wave-instr/CU) halves. grid = B*8 blocks of 1024.
// Adjacent slots share a label-region for ~97% of lanes -> keep the two-loop
// own-region skip + hoisted selector (bitwise-identical sums); straddling
// lanes fall back to a full-range loop with per-pair selector (extra terms
// are exact zeros: dg==0 for same-label pairs).
// KEY (unchanged): 1/(1+exp(s*(a_i-a_j))) == (s>0 ? E_j : E_i)/(E_i+E_j).
__global__ __launch_bounds__(1024, 4) void k2_fused(const float* __restrict__ a,
                                                    const float* __restrict__ y,
                                                    const int* __restrict__ rank_part,
                                                    const float* __restrict__ row_sum,
                                                    float* __restrict__ out) {
    const int bx = blockIdx.x;
    const int r = bx >> 3, ic = bx & 7;
    const int tid = threadIdx.x;
    const int wid = tid >> 6, lane = tid & 63;

    __shared__ float4 sdat[N];          // y-sorted: (gain*c, ilr, e^a, orig idx)
    __shared__ int4 hist4[16];          // per-wave popc(b1..b4)
    __shared__ float wt[16];

    const float ai = a[r * N + tid];
    const float yi = y[r * N + tid];

    int cnt = 0;
#pragma unroll
    for (int jc = 0; jc < JC; jc++) cnt += rank_part[(jc * B + r) * N + tid];
    // pi = cnt+1; ilr = 1/log2(pi+1) = 1/log2(cnt+2)
    const float ilr = __builtin_amdgcn_rcpf(__log2f((float)(cnt + 2)));
    const float Ei = EXP2F(ai * LOG2E);      // e^a_i, once per element

    // y histogram via wave ballots; only cumulative popcounts stored.
    const unsigned long long b1 = __ballot(yi >= 1.0f);
    const unsigned long long b2 = __ballot(yi >= 2.0f);
    const unsigned long long b3 = __ballot(yi >= 3.0f);
    const unsigned long long b4 = __ballot(yi >= 4.0f);
    if (lane == 0)
        hist4[wid] = make_int4(__popcll(b1), __popcll(b2), __popcll(b3), __popcll(b4));
    __syncthreads();                         // barrier A

    // every thread: cumulative totals (broadcast LDS reads)
    int p1 = 0, p2 = 0, p3 = 0, p4 = 0;
#pragma unroll
    for (int w = 0; w < 16; w++) {
        const int4 h = hist4[w];
        p1 += h.x; p2 += h.y; p3 += h.z; p4 += h.w;
    }

    // idcg from sorted-descending y at virtual position tid
    const int vv = (tid < p4) ? 4 : (tid < p3) ? 3 : (tid < p2) ? 2 : (tid < p1) ? 1 : 0;
    float term = (float)((1 << vv) - 1) *
                 __builtin_amdgcn_rcpf(__log2f((float)(tid + 2)));
#pragma unroll
    for (int off = 32; off >= 1; off >>= 1) term += __shfl_down(term, off, 64);
    if (lane == 0) wt[wid] = term;

    if (bx == 0 && wid == 0) {  // loss = sum(a): reduce K1's 32 row sums
        float s = (lane < B) ? row_sum[lane] : 0.f;
#pragma unroll
        for (int off = 16; off >= 1; off >>= 1) s += __shfl_down(s, off, 64);
        if (lane == 0) out[0] = s;
    }
    __syncthreads();                         // barrier B

    float idcg = 0.f;
#pragma unroll
    for (int w = 0; w < 16; w++) idcg += wt[w];
    const float c = 2.0f * SIGMA / (idcg + FEPS);

    // scatter into y-descending slot order
    const int v = (int)yi;
    const unsigned long long mym =
        (v == 4) ? b4 : (v == 3) ? (b3 & ~b4) : (v == 2) ? (b2 & ~b3)
                      : (v == 1) ? (b1 & ~b2) : ~b1;
    const int start = (v == 4) ? 0 : (v == 3) ? p4 : (v == 2) ? p3
                    : (v == 1) ? p2 : p1;    // count(y > v)
    int prefix = 0;
    for (int w = 0; w < wid; w++) {          // per-wave count of label v, from diffs
        const int4 h = hist4[w];
        prefix += (v == 4) ? h.w : (v == 3) ? (h.z - h.w) : (v == 2) ? (h.y - h.z)
                : (v == 1) ? (h.x - h.y) : (64 - h.x);
    }
    const int slot = start + prefix + __popcll(mym & ((1ull << lane) - 1ull));

    sdat[slot] = make_float4(EXP2F(yi) * c, ilr, Ei, __int_as_float(tid));
    __syncthreads();                         // barrier C

    const int ii = tid >> 4;                 // 0..63
    const int s = tid & 15;                  // slice
    const int us0 = ic * 128 + 2 * ii;       // two ADJACENT owned slots
    const int us1 = us0 + 1;
    const float4 du0 = sdat[us0];
    const float4 du1 = sdat[us1];
    const int gu0 = (us0 < p4) ? 4 : (us0 < p3) ? 3 : (us0 < p2) ? 2 : (us0 < p1) ? 1 : 0;
    const int gu1 = (us1 < p4) ? 4 : (us1 < p3) ? 3 : (us1 < p2) ? 2 : (us1 < p1) ? 1 : 0;

    float acc0 = 0.f, acc1 = 0.f;
    if (gu0 == gu1) {
        // shared region bounds
        const int lo = (gu0 == 4) ? 0 : (gu0 == 3) ? p4 : (gu0 == 2) ? p3
                     : (gu0 == 1) ? p2 : p1;
        const int hi = (gu0 == 4) ? p4 : (gu0 == 3) ? p3 : (gu0 == 2) ? p2
                     : (gu0 == 1) ? p1 : N;
        float h0 = 0.f, h1 = 0.f;
        // y_j > y_u: dg < 0, selector = Eu (hoisted out of the loop)
        for (int u = s; u < lo; u += NSL) {
            const float4 dj = sdat[u];
            const float dg0 = du0.x - dj.x, dl0 = du0.y - dj.y;
            const float dg1 = du1.x - dj.x, dl1 = du1.y - dj.y;
            h0 = fmaf(dg0 * fabsf(dl0), __builtin_amdgcn_rcpf(du0.z + dj.z), h0);
            h1 = fmaf(dg1 * fabsf(dl1), __builtin_amdgcn_rcpf(du1.z + dj.z), h1);
        }
        // y_j < y_u: dg > 0, selector = E_j
        for (int u = hi + ((s - hi) & 15); u < N; u += NSL) {
            const float4 dj = sdat[u];
            const float dg0 = du0.x - dj.x, dl0 = du0.y - dj.y;
            const float dg1 = du1.x - dj.x, dl1 = du1.y - dj.y;
            acc0 = fmaf(dg0 * fabsf(dl0) * dj.z, __builtin_amdgcn_rcpf(du0.z + dj.z), acc0);
            acc1 = fmaf(dg1 * fabsf(dl1) * dj.z, __builtin_amdgcn_rcpf(du1.z + dj.z), acc1);
        }
        acc0 = fmaf(h0, du0.z, acc0);
        acc1 = fmaf(h1, du1.z, acc1);
    } else {
        // region-straddling lane (~3%): full range, per-pair selector;
        // same-label pairs contribute exact 0 (dg == 0).
        for (int u = s; u < N; u += NSL) {
            const float4 dj = sdat[u];
            const float dg0 = du0.x - dj.x, dl0 = du0.y - dj.y;
            const float sel0 = (dg0 >= 0.f) ? dj.z : du0.z;
            acc0 = fmaf(dg0 * fabsf(dl0) * sel0, __builtin_amdgcn_rcpf(du0.z + dj.z), acc0);
            const float dg1 = du1.x - dj.x, dl1 = du1.y - dj.y;
            const float sel1 = (dg1 >= 0.f) ? dj.z : du1.z;
            acc1 = fmaf(dg1 * fabsf(dl1) * sel1, __builtin_amdgcn_rcpf(du1.z + dj.z), acc1);
        }
    }
#pragma unroll
    for (int off = 8; off >= 1; off >>= 1) {
        acc0 += __shfl_down(acc0, off, 16);
        acc1 += __shfl_down(acc1, off, 16);
    }
    if (s == 0) {
        out[1 + r * N + __float_as_int(du0.w)] = -acc0;
        out[1 + r * N + __float_as_int(du1.w)] = -acc1;
    }
}

extern "C" void kernel_launch(void* const* d_in, const int* in_sizes, int n_in,
                              void* d_out, int out_size, void* d_ws, size_t ws_size,
                              hipStream_t stream) {
    (void)in_sizes; (void)n_in; (void)out_size; (void)ws_size;
    const float* a = (const float*)d_in[0];
    const float* y = (const float*)d_in[1];
    float* out = (float*)d_out;

    int* rank_part = (int*)d_ws;                                    // 1 MB
    float* row_sum = (float*)((char*)d_ws + (size_t)JC * B * N * sizeof(int));

    hipLaunchKernelGGL(k1_rank, dim3(B * JC), dim3(256), 0, stream, a, rank_part, row_sum);
    hipLaunchKernelGGL(k2_fused, dim3(B * 8), dim3(1024), 0, stream, a, y, rank_part,
                       row_sum, out);
}

// Round 4
// 79.933 us; speedup vs baseline: 1.0203x; 1.0203x over previous
//
#include <hip/hip_runtime.h>
#include <math.h>

#define N 1024
#define B 32
#define JC 8            // k1 j-chunks per row
#define K1CHUNK 128     // N / JC
#define NSL 16          // j-slices per i (tid & 15)
#define SIGMA 1.0f
#define FEPS 1.1920928955078125e-07f   // np.finfo(float32).eps
#define LOG2E 1.4426950408889634f

#if defined(__has_builtin) && __has_builtin(__builtin_amdgcn_exp2f)
#define EXP2F(x) __builtin_amdgcn_exp2f(x)
#else
#define EXP2F(x) exp2f(x)
#endif

// Monotone-increasing uint mapping of float (no NaNs in input).
__device__ __forceinline__ unsigned fkey(float f) {
    unsigned u = __float_as_uint(f);
    return (u & 0x80000000u) ? ~u : (u | 0x80000000u);
}

// K1: partial stable-descending-rank counts over j-chunks; per-row sum(a).
// Rank condition (a_j > a_i) || (a_j == a_i && j < i) folded into ONE u64
// compare: K = (fkey(a) << 32) | (N-1-idx);  K_j > K_i  <=>  rank condition.
__global__ __launch_bounds__(256) void k1_rank(const float* __restrict__ a,
                                               int* __restrict__ rank_part,
                                               float* __restrict__ row_sum) {
    const int bx = blockIdx.x;
    const int r = bx >> 3, jc = bx & 7;
    const int tid = threadIdx.x;
    const float* __restrict__ arow = a + r * N;

    __shared__ unsigned long long sK[K1CHUNK];
    if (tid < K1CHUNK) {
        const int jg = jc * K1CHUNK + tid;
        sK[tid] = ((unsigned long long)fkey(arow[jg]) << 32) |
                  (unsigned)(N - 1 - jg);
    }

    float ai[4];
    unsigned long long Ki[4];
    int ig[4];
#pragma unroll
    for (int k = 0; k < 4; k++) {
        ig[k] = tid + k * 256;
        ai[k] = arow[ig[k]];
        Ki[k] = ((unsigned long long)fkey(ai[k]) << 32) |
                (unsigned)(N - 1 - ig[k]);
    }
    __syncthreads();

    int cnt[4] = {0, 0, 0, 0};
#pragma unroll 4
    for (int j = 0; j < K1CHUNK; j++) {
        const unsigned long long Kj = sK[j];
#pragma unroll
        for (int k = 0; k < 4; k++) cnt[k] += (Kj > Ki[k]) ? 1 : 0;
    }
#pragma unroll
    for (int k = 0; k < 4; k++)
        rank_part[(jc * B + r) * N + ig[k]] = cnt[k];

    if (jc == 0) {
        float s = ai[0] + ai[1] + ai[2] + ai[3];
#pragma unroll
        for (int off = 32; off >= 1; off >>= 1) s += __shfl_down(s, off, 64);
        __shared__ float wsum[4];
        if ((tid & 63) == 0) wsum[tid >> 6] = s;
        __syncthreads();
        if (tid == 0) row_sum[r] = wsum[0] + wsum[1] + wsum[2] + wsum[3];
    }
}

// K2_PREP: phase A ONCE per row (was 16x redundant inside every k2 block).
// grid = B blocks of 1024. Computes rank->ilr, e^a, ballot-sort by y
// (descending, stable), idcg -> c, and writes the y-sorted per-element
// float4 (gain*c, ilr, e^a, orig idx) rows + region bounds to workspace.
// Also emits the placeholder loss out[0].
__global__ __launch_bounds__(1024) void k2_prep(const float* __restrict__ a,
                                                const float* __restrict__ y,
                                                const int* __restrict__ rank_part,
                                                const float* __restrict__ row_sum,
                                                float4* __restrict__ sdat_g,
                                                int4* __restrict__ pbounds,
                                                float* __restrict__ out) {
    const int r = blockIdx.x;
    const int tid = threadIdx.x;
    const int wid = tid >> 6, lane = tid & 63;

    __shared__ int4 hist4[16];          // per-wave popc(b1..b4)
    __shared__ float wt[16];

    const float ai = a[r * N + tid];
    const float yi = y[r * N + tid];

    int cnt = 0;
#pragma unroll
    for (int jc = 0; jc < JC; jc++) cnt += rank_part[(jc * B + r) * N + tid];
    // pi = cnt+1; ilr = 1/log2(pi+1) = 1/log2(cnt+2)
    const float ilr = __builtin_amdgcn_rcpf(__log2f((float)(cnt + 2)));
    const float Ei = EXP2F(ai * LOG2E);      // e^a_i, once per element

    // y histogram via wave ballots; only cumulative popcounts stored.
    const unsigned long long b1 = __ballot(yi >= 1.0f);
    const unsigned long long b2 = __ballot(yi >= 2.0f);
    const unsigned long long b3 = __ballot(yi >= 3.0f);
    const unsigned long long b4 = __ballot(yi >= 4.0f);
    if (lane == 0)
        hist4[wid] = make_int4(__popcll(b1), __popcll(b2), __popcll(b3), __popcll(b4));
    __syncthreads();                         // barrier A

    int p1 = 0, p2 = 0, p3 = 0, p4 = 0;
#pragma unroll
    for (int w = 0; w < 16; w++) {
        const int4 h = hist4[w];
        p1 += h.x; p2 += h.y; p3 += h.z; p4 += h.w;
    }

    // idcg from sorted-descending y at virtual position tid
    const int vv = (tid < p4) ? 4 : (tid < p3) ? 3 : (tid < p2) ? 2 : (tid < p1) ? 1 : 0;
    float term = (float)((1 << vv) - 1) *
                 __builtin_amdgcn_rcpf(__log2f((float)(tid + 2)));
#pragma unroll
    for (int off = 32; off >= 1; off >>= 1) term += __shfl_down(term, off, 64);
    if (lane == 0) wt[wid] = term;

    if (r == 0 && wid == 0) {  // loss = sum(a): reduce K1's 32 row sums
        float s = (lane < B) ? row_sum[lane] : 0.f;
#pragma unroll
        for (int off = 16; off >= 1; off >>= 1) s += __shfl_down(s, off, 64);
        if (lane == 0) out[0] = s;
    }
    __syncthreads();                         // barrier B

    float idcg = 0.f;
#pragma unroll
    for (int w = 0; w < 16; w++) idcg += wt[w];
    const float c = 2.0f * SIGMA / (idcg + FEPS);

    // scatter into y-descending slot order (stable by original index)
    const int v = (int)yi;
    const unsigned long long mym =
        (v == 4) ? b4 : (v == 3) ? (b3 & ~b4) : (v == 2) ? (b2 & ~b3)
                      : (v == 1) ? (b1 & ~b2) : ~b1;
    const int start = (v == 4) ? 0 : (v == 3) ? p4 : (v == 2) ? p3
                    : (v == 1) ? p2 : p1;    // count(y > v)
    int prefix = 0;
    for (int w = 0; w < wid; w++) {          // per-wave count of label v, from diffs
        const int4 h = hist4[w];
        prefix += (v == 4) ? h.w : (v == 3) ? (h.z - h.w) : (v == 2) ? (h.y - h.z)
                : (v == 1) ? (h.x - h.y) : (64 - h.x);
    }
    const int slot = start + prefix + __popcll(mym & ((1ull << lane) - 1ull));

    sdat_g[r * N + slot] = make_float4(EXP2F(yi) * c, ilr, Ei, __int_as_float(tid));
    if (tid == 0) pbounds[r] = make_int4(p1, p2, p3, p4);
}

// K2_PAIR: pairwise gradient only. grid = B*64 blocks of 256 (8 blocks/CU =
// 32 waves/CU, the occupancy regime every winning round had). Block (r, seg)
// owns 16 i-slots; stages the y-sorted row (16 KB) into LDS from L2, then
// runs EXACTLY round-1's two-loop phase B (own-region skip, hoisted
// selector, same slice order -> identical accumulation order & absmax).
// KEY (unchanged): 1/(1+exp(s*(a_i-a_j))) == (s>0 ? E_j : E_i)/(E_i+E_j).
__global__ __launch_bounds__(256, 8) void k2_pair(const float4* __restrict__ sdat_g,
                                                  const int4* __restrict__ pbounds,
                                                  float* __restrict__ out) {
    const int bx = blockIdx.x;
    const int r = bx >> 6, seg = bx & 63;
    const int tid = threadIdx.x;

    __shared__ float4 sdat[N];
#pragma unroll
    for (int k = 0; k < 4; k++)
        sdat[tid + k * 256] = sdat_g[r * N + tid + k * 256];
    const int4 pb = pbounds[r];
    __syncthreads();

    const int p1 = pb.x, p2 = pb.y, p3 = pb.z, p4 = pb.w;
    const int us = seg * 16 + (tid >> 4);    // owned SLOT
    const int s = tid & 15;                  // slice
    const float4 du = sdat[us];
    int lo, hi;
    if (us < p4)      { lo = 0;  hi = p4; }
    else if (us < p3) { lo = p4; hi = p3; }
    else if (us < p2) { lo = p3; hi = p2; }
    else if (us < p1) { lo = p2; hi = p1; }
    else              { lo = p1; hi = N;  }

    float acc1 = 0.f, acc2 = 0.f;
    // y_j > y_u: dg < 0, selector = E_u (hoisted out of the loop)
    for (int u = s; u < lo; u += NSL) {
        const float4 dj = sdat[u];
        const float dg = du.x - dj.x;
        const float dl = du.y - dj.y;
        const float p  = dg * fabsf(dl);
        const float sum = du.z + dj.z;
        acc1 = fmaf(p, __builtin_amdgcn_rcpf(sum), acc1);
    }
    // y_j < y_u: dg > 0, selector = E_j
    for (int u = hi + ((s - hi) & 15); u < N; u += NSL) {
        const float4 dj = sdat[u];
        const float dg = du.x - dj.x;
        const float dl = du.y - dj.y;
        const float p  = dg * fabsf(dl) * dj.z;
        const float sum = du.z + dj.z;
        acc2 = fmaf(p, __builtin_amdgcn_rcpf(sum), acc2);
    }
    float acc = fmaf(acc1, du.z, acc2);
#pragma unroll
    for (int off = 8; off >= 1; off >>= 1) acc += __shfl_down(acc, off, 16);
    if (s == 0) out[1 + r * N + __float_as_int(du.w)] = -acc;
}

extern "C" void kernel_launch(void* const* d_in, const int* in_sizes, int n_in,
                              void* d_out, int out_size, void* d_ws, size_t ws_size,
                              hipStream_t stream) {
    (void)in_sizes; (void)n_in; (void)out_size; (void)ws_size;
    const float* a = (const float*)d_in[0];
    const float* y = (const float*)d_in[1];
    float* out = (float*)d_out;

    char* ws = (char*)d_ws;
    int* rank_part = (int*)ws;                                   // 1,048,576 B
    float* row_sum = (float*)(ws + 1048576);                     // 128 B
    float4* sdat_g = (float4*)(ws + 1048704);                    // 524,288 B (16B aligned)
    int4* pbounds = (int4*)(ws + 1572992);                       // 512 B

    hipLaunchKernelGGL(k1_rank, dim3(B * JC), dim3(256), 0, stream, a, rank_part, row_sum);
    hipLaunchKernelGGL(k2_prep, dim3(B), dim3(1024), 0, stream, a, y, rank_part,
                       row_sum, sdat_g, pbounds, out);
    hipLaunchKernelGGL(k2_pair, dim3(B * 64), dim3(256), 0, stream, sdat_g, pbounds, out);
}

// Round 5
// 76.466 us; speedup vs baseline: 1.0666x; 1.0453x over previous
//
#include <hip/hip_runtime.h>
#include <math.h>

#define N 1024
#define B 32
#define JC 8            // k1 j-chunks per row
#define K1CHUNK 128     // N / JC
#define NSL 32          // j-slices per i-pair (tid & 31)
#define SIGMA 1.0f
#define FEPS 1.1920928955078125e-07f   // np.finfo(float32).eps
#define LOG2E 1.4426950408889634f

#if defined(__has_builtin) && __has_builtin(__builtin_amdgcn_exp2f)
#define EXP2F(x) __builtin_amdgcn_exp2f(x)
#else
#define EXP2F(x) exp2f(x)
#endif

// Monotone-increasing uint mapping of float (no NaNs in input).
__device__ __forceinline__ unsigned fkey(float f) {
    unsigned u = __float_as_uint(f);
    return (u & 0x80000000u) ? ~u : (u | 0x80000000u);
}

// K1: partial stable-descending-rank counts over j-chunks; per-row sum(a).
// Rank condition (a_j > a_i) || (a_j == a_i && j < i) folded into ONE u64
// compare: K = (fkey(a) << 32) | (N-1-idx);  K_j > K_i  <=>  rank condition.
__global__ __launch_bounds__(256) void k1_rank(const float* __restrict__ a,
                                               int* __restrict__ rank_part,
                                               float* __restrict__ row_sum) {
    const int bx = blockIdx.x;
    const int r = bx >> 3, jc = bx & 7;
    const int tid = threadIdx.x;
    const float* __restrict__ arow = a + r * N;

    __shared__ unsigned long long sK[K1CHUNK];
    if (tid < K1CHUNK) {
        const int jg = jc * K1CHUNK + tid;
        sK[tid] = ((unsigned long long)fkey(arow[jg]) << 32) |
                  (unsigned)(N - 1 - jg);
    }

    float ai[4];
    unsigned long long Ki[4];
    int ig[4];
#pragma unroll
    for (int k = 0; k < 4; k++) {
        ig[k] = tid + k * 256;
        ai[k] = arow[ig[k]];
        Ki[k] = ((unsigned long long)fkey(ai[k]) << 32) |
                (unsigned)(N - 1 - ig[k]);
    }
    __syncthreads();

    int cnt[4] = {0, 0, 0, 0};
#pragma unroll 4
    for (int j = 0; j < K1CHUNK; j++) {
        const unsigned long long Kj = sK[j];
#pragma unroll
        for (int k = 0; k < 4; k++) cnt[k] += (Kj > Ki[k]) ? 1 : 0;
    }
#pragma unroll
    for (int k = 0; k < 4; k++)
        rank_part[(jc * B + r) * N + ig[k]] = cnt[k];

    if (jc == 0) {
        float s = ai[0] + ai[1] + ai[2] + ai[3];
#pragma unroll
        for (int off = 32; off >= 1; off >>= 1) s += __shfl_down(s, off, 64);
        __shared__ float wsum[4];
        if ((tid & 63) == 0) wsum[tid >> 6] = s;
        __syncthreads();
        if (tid == 0) row_sum[r] = wsum[0] + wsum[1] + wsum[2] + wsum[3];
    }
}

// K2: fused prep + pairwise gradient. grid = B*16 blocks of 1024, lb(1024,8)
// (2 blocks/CU, 8 waves/SIMD -- the empirically-required occupancy regime).
// Phase A (LEAN, no sort): rank -> ilr; ballot-histogram idcg (virtual sort,
// no scatter); sdat[tid] = (2^y*c, ilr, e^a) written IN PLACE.
// Phase B (latency-optimized): thread owns TWO i's (i0 = seg*64 + 2*(tid>>5),
// i1 = i0+1) and slice s = tid&31. FIXED 32-iteration loop, #pragma unroll 4
// -> 4 ds_read_b128 in flight (fine-grained lgkmcnt), each read feeds 2 pairs.
// Per-pair selector (R0 formulation, absmax-proven):
// 1/(1+exp(sg*(a_i-a_j))) == (sg>0 ? E_j : E_i)/(E_i+E_j),  sg = sign(y_i-y_j)
// and sign(dg) == sg since dg = c*(2^yi - 2^yj). Same-label pairs give exact 0.
__global__ __launch_bounds__(1024, 8) void k2_fused(const float* __restrict__ a,
                                                    const float* __restrict__ y,
                                                    const int* __restrict__ rank_part,
                                                    const float* __restrict__ row_sum,
                                                    float* __restrict__ out) {
    const int bx = blockIdx.x;
    const int r = bx >> 4, seg = bx & 15;
    const int tid = threadIdx.x;
    const int wid = tid >> 6, lane = tid & 63;

    __shared__ float4 sdat[N];          // per element: (gain*c, ilr, e^a, unused)
    __shared__ int4 hist4[16];          // per-wave popc(b1..b4)
    __shared__ float wt[16];

    const float ai = a[r * N + tid];
    const float yi = y[r * N + tid];

    int cnt = 0;
#pragma unroll
    for (int jc = 0; jc < JC; jc++) cnt += rank_part[(jc * B + r) * N + tid];
    // pi = cnt+1; ilr = 1/log2(pi+1) = 1/log2(cnt+2)
    const float ilr = __builtin_amdgcn_rcpf(__log2f((float)(cnt + 2)));
    const float Ei = EXP2F(ai * LOG2E);      // e^a_i, once per element

    // y histogram via wave ballots (for idcg only -- no scatter/sort needed)
    const unsigned long long b1 = __ballot(yi >= 1.0f);
    const unsigned long long b2 = __ballot(yi >= 2.0f);
    const unsigned long long b3 = __ballot(yi >= 3.0f);
    const unsigned long long b4 = __ballot(yi >= 4.0f);
    if (lane == 0)
        hist4[wid] = make_int4(__popcll(b1), __popcll(b2), __popcll(b3), __popcll(b4));
    __syncthreads();                         // barrier A

    int p1 = 0, p2 = 0, p3 = 0, p4 = 0;
#pragma unroll
    for (int w = 0; w < 16; w++) {
        const int4 h = hist4[w];
        p1 += h.x; p2 += h.y; p3 += h.z; p4 += h.w;
    }

    // idcg from sorted-descending y at virtual position tid
    const int vv = (tid < p4) ? 4 : (tid < p3) ? 3 : (tid < p2) ? 2 : (tid < p1) ? 1 : 0;
    float term = (float)((1 << vv) - 1) *
                 __builtin_amdgcn_rcpf(__log2f((float)(tid + 2)));
#pragma unroll
    for (int off = 32; off >= 1; off >>= 1) term += __shfl_down(term, off, 64);
    if (lane == 0) wt[wid] = term;

    if (bx == 0 && wid == 0) {  // loss = sum(a): reduce K1's 32 row sums
        float s = (lane < B) ? row_sum[lane] : 0.f;
#pragma unroll
        for (int off = 16; off >= 1; off >>= 1) s += __shfl_down(s, off, 64);
        if (lane == 0) out[0] = s;
    }
    __syncthreads();                         // barrier B

    float idcg = 0.f;
#pragma unroll
    for (int w = 0; w < 16; w++) idcg += wt[w];
    const float c = 2.0f * SIGMA / (idcg + FEPS);

    sdat[tid] = make_float4(EXP2F(yi) * c, ilr, Ei, 0.f);
    __syncthreads();                         // barrier C

    const int ii = tid >> 5;                 // 0..31: i-pair within segment
    const int s = tid & 31;                  // slice
    const int i0 = seg * 64 + 2 * ii;
    const float4 du0 = sdat[i0];
    const float4 du1 = sdat[i0 + 1];

    float acc0 = 0.f, acc1 = 0.f;
#pragma unroll 4
    for (int k = 0; k < N / NSL; k++) {
        const float4 dj = sdat[k * NSL + s];
        {
            const float dg = du0.x - dj.x;   // sign == sign(y_i0 - y_j); 0 if equal
            const float dl = du0.y - dj.y;
            const float sel = (dg >= 0.f) ? dj.z : du0.z;
            acc0 = fmaf(dg * fabsf(dl) * sel,
                        __builtin_amdgcn_rcpf(du0.z + dj.z), acc0);
        }
        {
            const float dg = du1.x - dj.x;
            const float dl = du1.y - dj.y;
            const float sel = (dg >= 0.f) ? dj.z : du1.z;
            acc1 = fmaf(dg * fabsf(dl) * sel,
                        __builtin_amdgcn_rcpf(du1.z + dj.z), acc1);
        }
    }
#pragma unroll
    for (int off = 16; off >= 1; off >>= 1) {
        acc0 += __shfl_down(acc0, off, 32);
        acc1 += __shfl_down(acc1, off, 32);
    }
    if (s == 0) {
        out[1 + r * N + i0]     = -acc0;
        out[1 + r * N + i0 + 1] = -acc1;
    }
}

extern "C" void kernel_launch(void* const* d_in, const int* in_sizes, int n_in,
                              void* d_out, int out_size, void* d_ws, size_t ws_size,
                              hipStream_t stream) {
    (void)in_sizes; (void)n_in; (void)out_size; (void)ws_size;
    const float* a = (const float*)d_in[0];
    const float* y = (const float*)d_in[1];
    float* out = (float*)d_out;

    int* rank_part = (int*)d_ws;                                    // 1 MB
    float* row_sum = (float*)((char*)d_ws + (size_t)JC * B * N * sizeof(int));

    hipLaunchKernelGGL(k1_rank, dim3(B * JC), dim3(256), 0, stream, a, rank_part, row_sum);
    hipLaunchKernelGGL(k2_fused, dim3(B * 16), dim3(1024), 0, stream, a, y, rank_part,
                       row_sum, out);
}